// Round 15
// baseline (163.020 us; speedup 1.0000x reference)
//
#include <hip/hip_runtime.h>
#include <math.h>

#define SS 7
#define NROIS 64
#define CC 2048
#define DD (SS*SS*CC)   // 100352
#define MM 64
#define NN 1024
#define NP1 128         // fc1 partials (one per kc)
#define KC2 16          // fc2 k-chunks (KCH=64, nkt=2)
#define KCH2 64
#define W1COLS 256      // fc1 per-block n-tile (1 KB/row strips -- R12 verified)
#define WSTRIDE 260     // LDS row stride in dwords (256 + 4 pad, 16B-aligned)
#define FC1_LDS (2 * 32 * WSTRIDE * 4)   // 66,560 B -> 2 blocks/CU

typedef float f32x4 __attribute__((ext_vector_type(4)));
typedef __bf16 bf16x8 __attribute__((ext_vector_type(8)));
typedef unsigned int uintx4 __attribute__((ext_vector_type(4)));

// Barrier WITHOUT the vmcnt(0) drain (verified win in R7/R11/R12).
#define LDS_BARRIER() do {                                         \
    asm volatile("s_waitcnt lgkmcnt(0)" ::: "memory");             \
    __builtin_amdgcn_s_barrier();                                  \
} while (0)

__device__ __forceinline__ unsigned short f2bf(float f){
    unsigned u = __builtin_bit_cast(unsigned, f);
    u += 0x7fffu + ((u >> 16) & 1u);           // RNE
    return (unsigned short)(u >> 16);
}
__device__ __forceinline__ float bf2f(unsigned short h){
    unsigned u = ((unsigned)h) << 16;
    return __builtin_bit_cast(float, u);
}
__device__ __forceinline__ void splitpk(float v0, float v1, unsigned& h, unsigned& l){
    __bf16 h0 = (__bf16)v0, h1 = (__bf16)v1;
    float r0 = v0 - (float)h0, r1 = v1 - (float)h1;
    __bf16 l0 = (__bf16)r0, l1 = (__bf16)r1;
    h = (unsigned)__builtin_bit_cast(unsigned short, h0) |
        ((unsigned)__builtin_bit_cast(unsigned short, h1) << 16);
    l = (unsigned)__builtin_bit_cast(unsigned short, l0) |
        ((unsigned)__builtin_bit_cast(unsigned short, l1) << 16);
}

// A-plane layout: interleaved hi/lo, [row][k/8][hi:8 shorts | lo:8 shorts].

// ---------------- Stage 1: crop + bilinear resize -> interleaved bf16 -------
__global__ void crop_kernel(const float* __restrict__ fm,
                            const float* __restrict__ boxes,
                            unsigned short* __restrict__ XI) {
    int roi = blockIdx.x;
    int p   = blockIdx.y;         // 0..48
    int sy = p / SS, sx = p % SS;
    const float* b = boxes + roi * 4;
    float x1 = fmaxf(0.f, rintf(b[0]));
    float y1 = fmaxf(0.f, rintf(b[1]));
    float x2 = fminf(15.f, rintf(b[2]));
    float y2 = fminf(15.f, rintf(b[3]));
    float h = y2 - y1, w = x2 - x1;
    float iy = ((sy + 0.5f) * h) / 7.0f - 0.5f;
    float ix = ((sx + 0.5f) * w) / 7.0f - 0.5f;
    iy = fminf(fmaxf(iy, 0.f), h - 1.f);
    ix = fminf(fmaxf(ix, 0.f), w - 1.f);
    float y0 = floorf(iy), x0 = floorf(ix);
    float fy = iy - y0,   fx = ix - x0;
    int y0i = (int)(y1 + y0);
    int y1i = min(y0i + 1, (int)(y1 + h - 1.f));
    int x0i = (int)(x1 + x0);
    int x1i = min(x0i + 1, (int)(x1 + w - 1.f));

    int c = threadIdx.x * 4;      // k index within row: p*CC + c
    const float4 v00 = *(const float4*)(fm + ((size_t)(y0i*16 + x0i))*CC + c);
    const float4 v01 = *(const float4*)(fm + ((size_t)(y0i*16 + x1i))*CC + c);
    const float4 v10 = *(const float4*)(fm + ((size_t)(y1i*16 + x0i))*CC + c);
    const float4 v11 = *(const float4*)(fm + ((size_t)(y1i*16 + x1i))*CC + c);
    float gy = 1.f - fy, gx = 1.f - fx;
    float o[4];
    o[0] = (v00.x*gy + v10.x*fy)*gx + (v01.x*gy + v11.x*fy)*fx;
    o[1] = (v00.y*gy + v10.y*fy)*gx + (v01.y*gy + v11.y*fy)*fx;
    o[2] = (v00.z*gy + v10.z*fy)*gx + (v01.z*gy + v11.z*fy)*fx;
    o[3] = (v00.w*gy + v10.w*fy)*gx + (v01.w*gy + v11.w*fy)*fx;
    uint2 hv, lv;
    splitpk(o[0], o[1], hv.x, lv.x);
    splitpk(o[2], o[3], hv.y, lv.y);
    int k = p * CC + c;
    size_t off = (size_t)roi * (2*DD) + (size_t)(k >> 3) * 16 + (k & 7);
    *(uint2*)(XI + off)     = hv;
    *(uint2*)(XI + off + 8) = lv;
}

// ---------------- Stage 2a: fc1 dbuf gld, 8 waves/block (R12 + wave-TLP) ----
// Grid (128 kc, 4 nb) = 512 blocks = 2/CU (dynamic LDS 66.5 KB) -- SAME DRAM
// pattern as R12 (1 KB contiguous per W row). 512 thr = 8 waves, wave tile
// 64m x 32n; each wave stages 4 rows (4 gld) -> 16 waves/CU of independent
// streams cover the vmcnt/barrier tails (2x R12's TLP). Counted vmcnt(4):
// next tile's 4 gld stay in flight across compute. fp32 in LDS; bf16 hi/lo
// split at read. 3-term: D += Ah*Bh + Ah*Bl + Al*Bh.
__global__ __launch_bounds__(512, 4)
void fc1_gld(const unsigned short* __restrict__ AI,
             const float* __restrict__ Wm, float* __restrict__ P) {
    const int kc = blockIdx.x;                       // 0..127
    const int nb = blockIdx.y;                       // 0..3
    const int kt_cnt = 24 + (kc < 64 ? 1 : 0);
    const int k0 = (kc * 24 + (kc < 64 ? kc : 64)) * 32;

    const int t = threadIdx.x;                       // 0..511
    const int lane = t & 63, wv = t >> 6;            // wv 0..7
    const int ln = lane & 15;
    const int koff = (lane >> 4) * 8;

    extern __shared__ float WS[];                    // 2 x [32][WSTRIDE]

    f32x4 acc[8];                                    // [nf*4+mf], static idx
    #pragma unroll
    for (int i = 0; i < 8; ++i) acc[i] = (f32x4){0.f, 0.f, 0.f, 0.f};

    size_t abase[4];
    #pragma unroll
    for (int mf = 0; mf < 4; ++mf)
        abase[mf] = (size_t)(mf * 16 + ln) * (2*DD) + (size_t)(k0 + koff) * 2;

    bf16x8 Ah[4], Al[4];

    const float* wtile = Wm + (size_t)k0 * NN + nb * W1COLS;
    // per-wave W staging: rows wv*4 .. wv*4+3, ONE gld per row (1 KB/instr)
    auto issueW = [&](int kt, int buf) {
        const float* g0 = wtile + ((size_t)kt * 32 + wv * 4) * NN + (lane << 2);
        float* l0 = WS + buf * (32 * WSTRIDE) + (wv * 4) * WSTRIDE;
        #pragma unroll
        for (int rr = 0; rr < 4; ++rr) {
            __builtin_amdgcn_global_load_lds(
                (const __attribute__((address_space(1))) void*)(g0 + (size_t)rr * NN),
                (__attribute__((address_space(3))) void*)(l0 + rr * WSTRIDE), 16, 0, 0);
        }
    };

    issueW(0, 0);                                    // prologue: tile 0 -> buf 0

    for (int kt = 0; kt < kt_cnt; ++kt) {
        const int cur = kt & 1;
        // A fragments for tile kt (L2-hot; retired by the counted wait below)
        #pragma unroll
        for (int mf = 0; mf < 4; ++mf) {
            Ah[mf] = *(const bf16x8*)(AI + abase[mf] + (size_t)kt * 64);
            Al[mf] = *(const bf16x8*)(AI + abase[mf] + (size_t)kt * 64 + 8);
        }
        if (kt + 1 < kt_cnt) {
            issueW(kt + 1, 1 - cur);                 // 4 newest stay in flight
            asm volatile("s_waitcnt vmcnt(4)" ::: "memory");
        } else {
            asm volatile("s_waitcnt vmcnt(0)" ::: "memory");
        }
        __builtin_amdgcn_s_barrier();                // tile kt fully in LDS
        // ---- compute tile kt from buf[cur]
        const float* B = WS + cur * (32 * WSTRIDE);
        #pragma unroll
        for (int nf = 0; nf < 2; ++nf) {
            const int cb = koff * WSTRIDE + wv * 32 + nf * 16 + ln;
            float f0 = B[cb + 0*WSTRIDE];
            float f1 = B[cb + 1*WSTRIDE];
            float f2 = B[cb + 2*WSTRIDE];
            float f3 = B[cb + 3*WSTRIDE];
            float f4 = B[cb + 4*WSTRIDE];
            float f5 = B[cb + 5*WSTRIDE];
            float f6 = B[cb + 6*WSTRIDE];
            float f7 = B[cb + 7*WSTRIDE];
            unsigned h01,l01,h23,l23,h45,l45,h67,l67;
            splitpk(f0, f1, h01, l01);
            splitpk(f2, f3, h23, l23);
            splitpk(f4, f5, h45, l45);
            splitpk(f6, f7, h67, l67);
            bf16x8 Bh = __builtin_bit_cast(bf16x8, (uintx4){h01, h23, h45, h67});
            bf16x8 Bl = __builtin_bit_cast(bf16x8, (uintx4){l01, l23, l45, l67});
            #pragma unroll
            for (int mf = 0; mf < 4; ++mf) {
                acc[nf*4+mf] = __builtin_amdgcn_mfma_f32_16x16x32_bf16(Ah[mf], Bh, acc[nf*4+mf], 0, 0, 0);
                acc[nf*4+mf] = __builtin_amdgcn_mfma_f32_16x16x32_bf16(Ah[mf], Bl, acc[nf*4+mf], 0, 0, 0);
                acc[nf*4+mf] = __builtin_amdgcn_mfma_f32_16x16x32_bf16(Al[mf], Bh, acc[nf*4+mf], 0, 0, 0);
            }
        }
        LDS_BARRIER();    // all reads of buf[cur] done -> next iter may gld into it
    }

    // ---- write partials: D row = (lane>>4)*4 + i, col = lane&15 (verified)
    const int orb = (lane >> 4) * 4;
    #pragma unroll
    for (int nf = 0; nf < 2; ++nf) {
        int col = nb * W1COLS + wv * 32 + nf * 16 + ln;
        #pragma unroll
        for (int mf = 0; mf < 4; ++mf) {
            #pragma unroll
            for (int i = 0; i < 4; ++i) {
                int m = mf * 16 + orb + i;
                P[((size_t)kc * MM + m) * NN + col] = acc[nf*4+mf][i];
            }
        }
    }
}

// ---------------- Stage 2b: generic FC (fc2) via bf16x2-split MFMA ----------
__global__ __launch_bounds__(256, 2)
void fc_mfma(const unsigned short* __restrict__ AI,
             const float* __restrict__ Wm, float* __restrict__ P,
             int rstride /*shorts*/, int kchunk) {
    const int kc = blockIdx.x, nb = blockIdx.y;
    const int n0 = nb * 128;
    const int k0 = kc * kchunk;
    const int t = threadIdx.x;
    const int lane = t & 63, wv = t >> 6;
    const int ln = lane & 15;
    const int koff = (lane >> 4) * 8;
    const int kp = t & 15, no = t >> 4;

    __shared__ unsigned short WTh[128][34];
    __shared__ unsigned short WTl[128][34];

    f32x4 acc[8];
    #pragma unroll
    for (int i = 0; i < 8; ++i) acc[i] = (f32x4){0.f, 0.f, 0.f, 0.f};

    size_t abase[4];
    #pragma unroll
    for (int mf = 0; mf < 4; ++mf)
        abase[mf] = (size_t)(mf * 16 + ln) * rstride + (size_t)((k0 + koff) >> 3) * 16;

    const float* wbase = Wm + (size_t)k0 * NN + n0 + no * 8;

    float4 wa[4], wb[4];
    bf16x8 Aah[4], Aal[4], Abh[4], Abl[4];

    auto loadW = [&](int kt, float4* r) {
        const float* p = wbase + (size_t)(kt * 32 + 2 * kp) * NN;
        r[0] = *(const float4*)(p);
        r[1] = *(const float4*)(p + 4);
        r[2] = *(const float4*)(p + NN);
        r[3] = *(const float4*)(p + NN + 4);
    };
    auto loadA = [&](int kt, bf16x8* Ah, bf16x8* Al) {
        const size_t kb = (size_t)kt * 64;
        #pragma unroll
        for (int mf = 0; mf < 4; ++mf) {
            Ah[mf] = *(const bf16x8*)(AI + abase[mf] + kb);
            Al[mf] = *(const bf16x8*)(AI + abase[mf] + kb + 8);
        }
    };
    auto stageW = [&](const float4* r) {
        const float* r0 = (const float*)&r[0];
        const float* r1 = (const float*)&r[2];
        #pragma unroll
        for (int e = 0; e < 8; ++e) {
            int n = no * 8 + e;
            unsigned h, l;
            splitpk(r0[e], r1[e], h, l);
            *(unsigned*)&WTh[n][2 * kp] = h;
            *(unsigned*)&WTl[n][2 * kp] = l;
        }
    };

#define MFMA_PHASE(AH, AL)                                                     \
    {                                                                          \
        _Pragma("unroll")                                                      \
        for (int nf = 0; nf < 2; ++nf) {                                       \
            bf16x8 Bh = *(const bf16x8*)&WTh[wv * 32 + nf * 16 + ln][koff];    \
            bf16x8 Bl = *(const bf16x8*)&WTl[wv * 32 + nf * 16 + ln][koff];    \
            _Pragma("unroll")                                                  \
            for (int mf = 0; mf < 4; ++mf) {                                   \
                acc[nf*4+mf] = __builtin_amdgcn_mfma_f32_16x16x32_bf16(AH[mf], Bh, acc[nf*4+mf], 0, 0, 0); \
                acc[nf*4+mf] = __builtin_amdgcn_mfma_f32_16x16x32_bf16(AH[mf], Bl, acc[nf*4+mf], 0, 0, 0); \
                acc[nf*4+mf] = __builtin_amdgcn_mfma_f32_16x16x32_bf16(AL[mf], Bh, acc[nf*4+mf], 0, 0, 0); \
            }                                                                  \
        }                                                                      \
    }

    const int nkt = kchunk >> 5;
    loadW(0, wa);
    loadW(1, wb);
    loadA(0, Aah, Aal);
    loadA(1, Abh, Abl);

    for (int ktp = 0; ktp + 1 < nkt; ktp += 2) {
        LDS_BARRIER();
        stageW(wa);
        if (ktp + 2 < nkt) loadW(ktp + 2, wa);
        LDS_BARRIER();
        MFMA_PHASE(Aah, Aal);
        if (ktp + 2 < nkt) loadA(ktp + 2, Aah, Aal);
        LDS_BARRIER();
        stageW(wb);
        if (ktp + 3 < nkt) loadW(ktp + 3, wb);
        LDS_BARRIER();
        MFMA_PHASE(Abh, Abl);
        if (ktp + 3 < nkt) loadA(ktp + 3, Abh, Abl);
    }
    if (nkt & 1) {
        LDS_BARRIER();
        stageW(wa);
        LDS_BARRIER();
        MFMA_PHASE(Aah, Aal);
    }
#undef MFMA_PHASE

    const int orb = (lane >> 4) * 4;
    #pragma unroll
    for (int nf = 0; nf < 2; ++nf) {
        int col = n0 + wv * 32 + nf * 16 + ln;
        #pragma unroll
        for (int mf = 0; mf < 4; ++mf) {
            #pragma unroll
            for (int i = 0; i < 4; ++i) {
                int m = mf * 16 + orb + i;
                P[((size_t)kc * MM + m) * NN + col] = acc[nf*4+mf][i];
            }
        }
    }
}

// ---------------- Stage 3: reduce 128 partials + bias + relu -> interleaved -
__global__ void reduce_bias_split(const float* __restrict__ P,
                                  const float* __restrict__ bias,
                                  unsigned short* __restrict__ YI) {
    int idx = blockIdx.x * 256 + threadIdx.x;   // 0..65535
    int n = idx & (NN - 1);
    int m = idx >> 10;
    float s0 = bias[n], s1 = 0.f, s2 = 0.f, s3 = 0.f;
    float s4 = 0.f, s5 = 0.f, s6 = 0.f, s7 = 0.f;
    for (int kc = 0; kc < NP1; kc += 8) {
        s0 += P[(size_t)(kc + 0) * (MM*NN) + idx];
        s1 += P[(size_t)(kc + 1) * (MM*NN) + idx];
        s2 += P[(size_t)(kc + 2) * (MM*NN) + idx];
        s3 += P[(size_t)(kc + 3) * (MM*NN) + idx];
        s4 += P[(size_t)(kc + 4) * (MM*NN) + idx];
        s5 += P[(size_t)(kc + 5) * (MM*NN) + idx];
        s6 += P[(size_t)(kc + 6) * (MM*NN) + idx];
        s7 += P[(size_t)(kc + 7) * (MM*NN) + idx];
    }
    float s = ((s0 + s1) + (s2 + s3)) + ((s4 + s5) + (s6 + s7));
    s = fmaxf(s, 0.f);
    unsigned short h = f2bf(s);
    size_t off = (size_t)m * (2*NN) + (size_t)(n >> 3) * 16 + (n & 7);
    YI[off]     = h;
    YI[off + 8] = f2bf(s - bf2f(h));
}

// ---------------- Stage 4: fused P2-reduce + bias + relu + heads ------------
__global__ void heads_kernel(const float* __restrict__ P2,
                             const float* __restrict__ b2,
                             const float* __restrict__ Wc, const float* __restrict__ bc,
                             const float* __restrict__ Wb, const float* __restrict__ bb,
                             float* __restrict__ out) {
    int m = blockIdx.x;
    int t = threadIdx.x;   // 256
    float a[6] = {0,0,0,0,0,0};
    #pragma unroll
    for (int j = 0; j < 4; ++j) {
        int n = j * 256 + t;
        float s = b2[n];
        #pragma unroll
        for (int kc = 0; kc < KC2; ++kc)
            s += P2[((size_t)kc * MM + m) * NN + n];
        s = fmaxf(s, 0.f);
        a[0] += s * Wc[n*2 + 0];
        a[1] += s * Wc[n*2 + 1];
        a[2] += s * Wb[n*4 + 0];
        a[3] += s * Wb[n*4 + 1];
        a[4] += s * Wb[n*4 + 2];
        a[5] += s * Wb[n*4 + 3];
    }
    __shared__ float red[6][256];
    #pragma unroll
    for (int j = 0; j < 6; ++j) red[j][t] = a[j];
    __syncthreads();
    for (int s = 128; s > 0; s >>= 1) {
        if (t < s) {
            #pragma unroll
            for (int j = 0; j < 6; ++j) red[j][t] += red[j][t + s];
        }
        __syncthreads();
    }
    if (t == 0) {
        float l0 = red[0][0] + bc[0], l1 = red[1][0] + bc[1];
        float mx = fmaxf(l0, l1);
        float e0 = expf(l0 - mx), e1 = expf(l1 - mx);
        float inv = 1.f / (e0 + e1);
        out[m*2 + 0] = e0 * inv;
        out[m*2 + 1] = e1 * inv;
        out[128 + m*4 + 0] = red[2][0] + bb[0];
        out[128 + m*4 + 1] = red[3][0] + bb[1];
        out[128 + m*4 + 2] = red[4][0] + bb[2];
        out[128 + m*4 + 3] = red[5][0] + bb[3];
    }
}

extern "C" void kernel_launch(void* const* d_in, const int* in_sizes, int n_in,
                              void* d_out, int out_size, void* d_ws, size_t ws_size,
                              hipStream_t stream) {
    const float* fm    = (const float*)d_in[0];
    const float* boxes = (const float*)d_in[1];
    const float* W1    = (const float*)d_in[2];
    const float* b1    = (const float*)d_in[3];
    const float* W2    = (const float*)d_in[4];
    const float* b2    = (const float*)d_in[5];
    const float* Wc    = (const float*)d_in[6];
    const float* bc    = (const float*)d_in[7];
    const float* Wb    = (const float*)d_in[8];
    const float* bb    = (const float*)d_in[9];
    float* out = (float*)d_out;
    char* ws = (char*)d_ws;

    const size_t XIB = (size_t)NROIS * (2*DD) * sizeof(unsigned short);  // 25,690,112
    const size_t P1B = (size_t)NP1 * MM * NN * sizeof(float);            // 33,554,432
    unsigned short* XI  = (unsigned short*)ws;
    float*          P1  = (float*)(ws + XIB);
    unsigned short* h1I = (unsigned short*)(ws + XIB + P1B);             // 262,144 B
    float*          P2  = (float*)(ws + XIB + P1B + 262144);             // 4,194,304 B

    hipFuncSetAttribute((const void*)fc1_gld,
                        hipFuncAttributeMaxDynamicSharedMemorySize, FC1_LDS);

    crop_kernel<<<dim3(NROIS, SS*SS), 512, 0, stream>>>(fm, boxes, XI);
    fc1_gld<<<dim3(NP1, 4), 512, FC1_LDS, stream>>>(XI, W1, P1);
    reduce_bias_split<<<(MM*NN)/256, 256, 0, stream>>>(P1, b1, h1I);
    fc_mfma<<<dim3(KC2, 8), 256, 0, stream>>>(h1I, W2, P2, 2*NN, KCH2);
    heads_kernel<<<NROIS, 256, 0, stream>>>(P2, b2, Wc, bc, Wb, bb, out);
}

// Round 16
// 132.008 us; speedup vs baseline: 1.2349x; 1.2349x over previous
//
#include <hip/hip_runtime.h>
#include <math.h>

#define SS 7
#define NROIS 64
#define CC 2048
#define DD (SS*SS*CC)   // 100352
#define MM 64
#define NN 1024
#define NP1 128         // fc1 partials (one per kc)
#define KC2 16          // fc2 k-chunks (KCH=64, nkt=2)
#define KCH2 64
#define W1COLS 256      // fc1 per-block n-tile
#define WSTRIDE 260     // LDS row stride in dwords (256 + 4 pad, 16B-aligned)
#define FC1_LDS (2 * 32 * WSTRIDE * 4)   // 66,560 B -> 2 blocks/CU

typedef float f32x4 __attribute__((ext_vector_type(4)));
typedef __bf16 bf16x8 __attribute__((ext_vector_type(8)));
typedef unsigned int uintx4 __attribute__((ext_vector_type(4)));

// Barrier WITHOUT the vmcnt(0) drain (verified win in R7/R11/R12).
#define LDS_BARRIER() do {                                         \
    asm volatile("s_waitcnt lgkmcnt(0)" ::: "memory");             \
    __builtin_amdgcn_s_barrier();                                  \
} while (0)

__device__ __forceinline__ unsigned short f2bf(float f){
    unsigned u = __builtin_bit_cast(unsigned, f);
    u += 0x7fffu + ((u >> 16) & 1u);           // RNE
    return (unsigned short)(u >> 16);
}
__device__ __forceinline__ float bf2f(unsigned short h){
    unsigned u = ((unsigned)h) << 16;
    return __builtin_bit_cast(float, u);
}
__device__ __forceinline__ void splitpk(float v0, float v1, unsigned& h, unsigned& l){
    __bf16 h0 = (__bf16)v0, h1 = (__bf16)v1;
    float r0 = v0 - (float)h0, r1 = v1 - (float)h1;
    __bf16 l0 = (__bf16)r0, l1 = (__bf16)r1;
    h = (unsigned)__builtin_bit_cast(unsigned short, h0) |
        ((unsigned)__builtin_bit_cast(unsigned short, h1) << 16);
    l = (unsigned)__builtin_bit_cast(unsigned short, l0) |
        ((unsigned)__builtin_bit_cast(unsigned short, l1) << 16);
}

// A-plane layout: interleaved hi/lo, [row][k/8][hi:8 shorts | lo:8 shorts].

// ---------------- Stage 1: crop + bilinear resize -> interleaved bf16 -------
__global__ void crop_kernel(const float* __restrict__ fm,
                            const float* __restrict__ boxes,
                            unsigned short* __restrict__ XI) {
    int roi = blockIdx.x;
    int p   = blockIdx.y;         // 0..48
    int sy = p / SS, sx = p % SS;
    const float* b = boxes + roi * 4;
    float x1 = fmaxf(0.f, rintf(b[0]));
    float y1 = fmaxf(0.f, rintf(b[1]));
    float x2 = fminf(15.f, rintf(b[2]));
    float y2 = fminf(15.f, rintf(b[3]));
    float h = y2 - y1, w = x2 - x1;
    float iy = ((sy + 0.5f) * h) / 7.0f - 0.5f;
    float ix = ((sx + 0.5f) * w) / 7.0f - 0.5f;
    iy = fminf(fmaxf(iy, 0.f), h - 1.f);
    ix = fminf(fmaxf(ix, 0.f), w - 1.f);
    float y0 = floorf(iy), x0 = floorf(ix);
    float fy = iy - y0,   fx = ix - x0;
    int y0i = (int)(y1 + y0);
    int y1i = min(y0i + 1, (int)(y1 + h - 1.f));
    int x0i = (int)(x1 + x0);
    int x1i = min(x0i + 1, (int)(x1 + w - 1.f));

    int c = threadIdx.x * 4;      // k index within row: p*CC + c
    const float4 v00 = *(const float4*)(fm + ((size_t)(y0i*16 + x0i))*CC + c);
    const float4 v01 = *(const float4*)(fm + ((size_t)(y0i*16 + x1i))*CC + c);
    const float4 v10 = *(const float4*)(fm + ((size_t)(y1i*16 + x0i))*CC + c);
    const float4 v11 = *(const float4*)(fm + ((size_t)(y1i*16 + x1i))*CC + c);
    float gy = 1.f - fy, gx = 1.f - fx;
    float o[4];
    o[0] = (v00.x*gy + v10.x*fy)*gx + (v01.x*gy + v11.x*fy)*fx;
    o[1] = (v00.y*gy + v10.y*fy)*gx + (v01.y*gy + v11.y*fy)*fx;
    o[2] = (v00.z*gy + v10.z*fy)*gx + (v01.z*gy + v11.z*fy)*fx;
    o[3] = (v00.w*gy + v10.w*fy)*gx + (v01.w*gy + v11.w*fy)*fx;
    uint2 hv, lv;
    splitpk(o[0], o[1], hv.x, lv.x);
    splitpk(o[2], o[3], hv.y, lv.y);
    int k = p * CC + c;
    size_t off = (size_t)roi * (2*DD) + (size_t)(k >> 3) * 16 + (k & 7);
    *(uint2*)(XI + off)     = hv;
    *(uint2*)(XI + off + 8) = lv;
}

// ---------------- Stage 2a: fc1 double-buffered gld (R12, verified best) ----
// Grid (128 kc, 4 nb) = 512 blocks = 2/CU (dynamic LDS 66.5 KB). 256 thr =
// 4 waves, wave tile 64m x 64n. Block kc owns 24-25 k-tiles (BK=32, 1 KB
// contiguous per W row). Double-buffered LDS + COUNTED vmcnt(8): tile kt+1's
// 8 gld/wave stay in flight through tile kt's compute -- the drain never hits
// 0 inside the loop. A-loads issued BEFORE the next-tile gld so in-order
// vmcnt(8) retires exactly gld(kt)+A(kt). fp32 in LDS; bf16 hi/lo split at
// read. 3-term: D += Ah*Bh + Ah*Bl + Al*Bh.
__global__ __launch_bounds__(256, 2)
void fc1_gld(const unsigned short* __restrict__ AI,
             const float* __restrict__ Wm, float* __restrict__ P) {
    const int kc = blockIdx.x;                       // 0..127
    const int nb = blockIdx.y;                       // 0..3
    const int kt_cnt = 24 + (kc < 64 ? 1 : 0);
    const int k0 = (kc * 24 + (kc < 64 ? kc : 64)) * 32;

    const int t = threadIdx.x;                       // 0..255
    const int lane = t & 63, wv = t >> 6;
    const int ln = lane & 15;
    const int koff = (lane >> 4) * 8;

    extern __shared__ float WS[];                    // 2 x [32][WSTRIDE]

    f32x4 acc[16];                                   // [nf*4+mf], static idx
    #pragma unroll
    for (int i = 0; i < 16; ++i) acc[i] = (f32x4){0.f, 0.f, 0.f, 0.f};

    size_t abase[4];
    #pragma unroll
    for (int mf = 0; mf < 4; ++mf)
        abase[mf] = (size_t)(mf * 16 + ln) * (2*DD) + (size_t)(k0 + koff) * 2;

    bf16x8 Ah[4], Al[4];

    // per-wave W staging: rows wv*8 .. wv*8+7, ONE gld per row (1 KB/instr)
    const float* wtile = Wm + (size_t)k0 * NN + nb * W1COLS;
    auto issueW = [&](int kt, int buf) {
        const float* g0 = wtile + ((size_t)kt * 32 + wv * 8) * NN + (lane << 2);
        float* l0 = WS + buf * (32 * WSTRIDE) + (wv * 8) * WSTRIDE;
        #pragma unroll
        for (int rr = 0; rr < 8; ++rr) {
            __builtin_amdgcn_global_load_lds(
                (const __attribute__((address_space(1))) void*)(g0 + (size_t)rr * NN),
                (__attribute__((address_space(3))) void*)(l0 + rr * WSTRIDE), 16, 0, 0);
        }
    };

    issueW(0, 0);                                    // prologue: tile 0 -> buf 0

    for (int kt = 0; kt < kt_cnt; ++kt) {
        const int cur = kt & 1;
        // A fragments for tile kt FIRST (older than next-tile gld in vmcnt)
        #pragma unroll
        for (int mf = 0; mf < 4; ++mf) {
            Ah[mf] = *(const bf16x8*)(AI + abase[mf] + (size_t)kt * 64);
            Al[mf] = *(const bf16x8*)(AI + abase[mf] + (size_t)kt * 64 + 8);
        }
        // next tile into the other buffer (read-finished last iter, barrier'd)
        if (kt + 1 < kt_cnt) issueW(kt + 1, 1 - cur);
        // wait: everything except the 8 newest (= next-tile gld) has landed
        asm volatile("s_waitcnt vmcnt(8)" ::: "memory");
        __builtin_amdgcn_s_barrier();                // all waves' tile-kt rows in
        // ---- compute tile kt from buf[cur]
        const float* B = WS + cur * (32 * WSTRIDE);
        #pragma unroll
        for (int nf = 0; nf < 4; ++nf) {
            const int cb = koff * WSTRIDE + wv * 64 + nf * 16 + ln;
            float f0 = B[cb + 0*WSTRIDE];
            float f1 = B[cb + 1*WSTRIDE];
            float f2 = B[cb + 2*WSTRIDE];
            float f3 = B[cb + 3*WSTRIDE];
            float f4 = B[cb + 4*WSTRIDE];
            float f5 = B[cb + 5*WSTRIDE];
            float f6 = B[cb + 6*WSTRIDE];
            float f7 = B[cb + 7*WSTRIDE];
            unsigned h01,l01,h23,l23,h45,l45,h67,l67;
            splitpk(f0, f1, h01, l01);
            splitpk(f2, f3, h23, l23);
            splitpk(f4, f5, h45, l45);
            splitpk(f6, f7, h67, l67);
            bf16x8 Bh = __builtin_bit_cast(bf16x8, (uintx4){h01, h23, h45, h67});
            bf16x8 Bl = __builtin_bit_cast(bf16x8, (uintx4){l01, l23, l45, l67});
            #pragma unroll
            for (int mf = 0; mf < 4; ++mf) {
                acc[nf*4+mf] = __builtin_amdgcn_mfma_f32_16x16x32_bf16(Ah[mf], Bh, acc[nf*4+mf], 0, 0, 0);
                acc[nf*4+mf] = __builtin_amdgcn_mfma_f32_16x16x32_bf16(Ah[mf], Bl, acc[nf*4+mf], 0, 0, 0);
                acc[nf*4+mf] = __builtin_amdgcn_mfma_f32_16x16x32_bf16(Al[mf], Bh, acc[nf*4+mf], 0, 0, 0);
            }
        }
        LDS_BARRIER();    // all reads of buf[cur] done -> next iter may gld into it
    }

    // ---- write partials: D row = (lane>>4)*4 + i, col = lane&15 (verified)
    const int orb = (lane >> 4) * 4;
    #pragma unroll
    for (int nf = 0; nf < 4; ++nf) {
        int col = nb * W1COLS + wv * 64 + nf * 16 + ln;
        #pragma unroll
        for (int mf = 0; mf < 4; ++mf) {
            #pragma unroll
            for (int i = 0; i < 4; ++i) {
                int m = mf * 16 + orb + i;
                P[((size_t)kc * MM + m) * NN + col] = acc[nf*4+mf][i];
            }
        }
    }
}

// ---------------- Stage 2b: generic FC (fc2) via bf16x2-split MFMA ----------
__global__ __launch_bounds__(256, 2)
void fc_mfma(const unsigned short* __restrict__ AI,
             const float* __restrict__ Wm, float* __restrict__ P,
             int rstride /*shorts*/, int kchunk) {
    const int kc = blockIdx.x, nb = blockIdx.y;
    const int n0 = nb * 128;
    const int k0 = kc * kchunk;
    const int t = threadIdx.x;
    const int lane = t & 63, wv = t >> 6;
    const int ln = lane & 15;
    const int koff = (lane >> 4) * 8;
    const int kp = t & 15, no = t >> 4;

    __shared__ unsigned short WTh[128][34];
    __shared__ unsigned short WTl[128][34];

    f32x4 acc[8];
    #pragma unroll
    for (int i = 0; i < 8; ++i) acc[i] = (f32x4){0.f, 0.f, 0.f, 0.f};

    size_t abase[4];
    #pragma unroll
    for (int mf = 0; mf < 4; ++mf)
        abase[mf] = (size_t)(mf * 16 + ln) * rstride + (size_t)((k0 + koff) >> 3) * 16;

    const float* wbase = Wm + (size_t)k0 * NN + n0 + no * 8;

    float4 wa[4], wb[4];
    bf16x8 Aah[4], Aal[4], Abh[4], Abl[4];

    auto loadW = [&](int kt, float4* r) {
        const float* p = wbase + (size_t)(kt * 32 + 2 * kp) * NN;
        r[0] = *(const float4*)(p);
        r[1] = *(const float4*)(p + 4);
        r[2] = *(const float4*)(p + NN);
        r[3] = *(const float4*)(p + NN + 4);
    };
    auto loadA = [&](int kt, bf16x8* Ah, bf16x8* Al) {
        const size_t kb = (size_t)kt * 64;
        #pragma unroll
        for (int mf = 0; mf < 4; ++mf) {
            Ah[mf] = *(const bf16x8*)(AI + abase[mf] + kb);
            Al[mf] = *(const bf16x8*)(AI + abase[mf] + kb + 8);
        }
    };
    auto stageW = [&](const float4* r) {
        const float* r0 = (const float*)&r[0];
        const float* r1 = (const float*)&r[2];
        #pragma unroll
        for (int e = 0; e < 8; ++e) {
            int n = no * 8 + e;
            unsigned h, l;
            splitpk(r0[e], r1[e], h, l);
            *(unsigned*)&WTh[n][2 * kp] = h;
            *(unsigned*)&WTl[n][2 * kp] = l;
        }
    };

#define MFMA_PHASE(AH, AL)                                                     \
    {                                                                          \
        _Pragma("unroll")                                                      \
        for (int nf = 0; nf < 2; ++nf) {                                       \
            bf16x8 Bh = *(const bf16x8*)&WTh[wv * 32 + nf * 16 + ln][koff];    \
            bf16x8 Bl = *(const bf16x8*)&WTl[wv * 32 + nf * 16 + ln][koff];    \
            _Pragma("unroll")                                                  \
            for (int mf = 0; mf < 4; ++mf) {                                   \
                acc[nf*4+mf] = __builtin_amdgcn_mfma_f32_16x16x32_bf16(AH[mf], Bh, acc[nf*4+mf], 0, 0, 0); \
                acc[nf*4+mf] = __builtin_amdgcn_mfma_f32_16x16x32_bf16(AH[mf], Bl, acc[nf*4+mf], 0, 0, 0); \
                acc[nf*4+mf] = __builtin_amdgcn_mfma_f32_16x16x32_bf16(AL[mf], Bh, acc[nf*4+mf], 0, 0, 0); \
            }                                                                  \
        }                                                                      \
    }

    const int nkt = kchunk >> 5;
    loadW(0, wa);
    loadW(1, wb);
    loadA(0, Aah, Aal);
    loadA(1, Abh, Abl);

    for (int ktp = 0; ktp + 1 < nkt; ktp += 2) {
        LDS_BARRIER();
        stageW(wa);
        if (ktp + 2 < nkt) loadW(ktp + 2, wa);
        LDS_BARRIER();
        MFMA_PHASE(Aah, Aal);
        if (ktp + 2 < nkt) loadA(ktp + 2, Aah, Aal);
        LDS_BARRIER();
        stageW(wb);
        if (ktp + 3 < nkt) loadW(ktp + 3, wb);
        LDS_BARRIER();
        MFMA_PHASE(Abh, Abl);
        if (ktp + 3 < nkt) loadA(ktp + 3, Abh, Abl);
    }
    if (nkt & 1) {
        LDS_BARRIER();
        stageW(wa);
        LDS_BARRIER();
        MFMA_PHASE(Aah, Aal);
    }
#undef MFMA_PHASE

    const int orb = (lane >> 4) * 4;
    #pragma unroll
    for (int nf = 0; nf < 2; ++nf) {
        int col = n0 + wv * 32 + nf * 16 + ln;
        #pragma unroll
        for (int mf = 0; mf < 4; ++mf) {
            #pragma unroll
            for (int i = 0; i < 4; ++i) {
                int m = mf * 16 + orb + i;
                P[((size_t)kc * MM + m) * NN + col] = acc[nf*4+mf][i];
            }
        }
    }
}

// ---------------- Stage 3: reduce 128 partials + bias + relu -> interleaved -
__global__ void reduce_bias_split(const float* __restrict__ P,
                                  const float* __restrict__ bias,
                                  unsigned short* __restrict__ YI) {
    int idx = blockIdx.x * 256 + threadIdx.x;   // 0..65535
    int n = idx & (NN - 1);
    int m = idx >> 10;
    float s0 = bias[n], s1 = 0.f, s2 = 0.f, s3 = 0.f;
    float s4 = 0.f, s5 = 0.f, s6 = 0.f, s7 = 0.f;
    for (int kc = 0; kc < NP1; kc += 8) {
        s0 += P[(size_t)(kc + 0) * (MM*NN) + idx];
        s1 += P[(size_t)(kc + 1) * (MM*NN) + idx];
        s2 += P[(size_t)(kc + 2) * (MM*NN) + idx];
        s3 += P[(size_t)(kc + 3) * (MM*NN) + idx];
        s4 += P[(size_t)(kc + 4) * (MM*NN) + idx];
        s5 += P[(size_t)(kc + 5) * (MM*NN) + idx];
        s6 += P[(size_t)(kc + 6) * (MM*NN) + idx];
        s7 += P[(size_t)(kc + 7) * (MM*NN) + idx];
    }
    float s = ((s0 + s1) + (s2 + s3)) + ((s4 + s5) + (s6 + s7));
    s = fmaxf(s, 0.f);
    unsigned short h = f2bf(s);
    size_t off = (size_t)m * (2*NN) + (size_t)(n >> 3) * 16 + (n & 7);
    YI[off]     = h;
    YI[off + 8] = f2bf(s - bf2f(h));
}

// ---------------- Stage 4: fused P2-reduce + bias + relu + heads ------------
__global__ void heads_kernel(const float* __restrict__ P2,
                             const float* __restrict__ b2,
                             const float* __restrict__ Wc, const float* __restrict__ bc,
                             const float* __restrict__ Wb, const float* __restrict__ bb,
                             float* __restrict__ out) {
    int m = blockIdx.x;
    int t = threadIdx.x;   // 256
    float a[6] = {0,0,0,0,0,0};
    #pragma unroll
    for (int j = 0; j < 4; ++j) {
        int n = j * 256 + t;
        float s = b2[n];
        #pragma unroll
        for (int kc = 0; kc < KC2; ++kc)
            s += P2[((size_t)kc * MM + m) * NN + n];
        s = fmaxf(s, 0.f);
        a[0] += s * Wc[n*2 + 0];
        a[1] += s * Wc[n*2 + 1];
        a[2] += s * Wb[n*4 + 0];
        a[3] += s * Wb[n*4 + 1];
        a[4] += s * Wb[n*4 + 2];
        a[5] += s * Wb[n*4 + 3];
    }
    __shared__ float red[6][256];
    #pragma unroll
    for (int j = 0; j < 6; ++j) red[j][t] = a[j];
    __syncthreads();
    for (int s = 128; s > 0; s >>= 1) {
        if (t < s) {
            #pragma unroll
            for (int j = 0; j < 6; ++j) red[j][t] += red[j][t + s];
        }
        __syncthreads();
    }
    if (t == 0) {
        float l0 = red[0][0] + bc[0], l1 = red[1][0] + bc[1];
        float mx = fmaxf(l0, l1);
        float e0 = expf(l0 - mx), e1 = expf(l1 - mx);
        float inv = 1.f / (e0 + e1);
        out[m*2 + 0] = e0 * inv;
        out[m*2 + 1] = e1 * inv;
        out[128 + m*4 + 0] = red[2][0] + bb[0];
        out[128 + m*4 + 1] = red[3][0] + bb[1];
        out[128 + m*4 + 2] = red[4][0] + bb[2];
        out[128 + m*4 + 3] = red[5][0] + bb[3];
    }
}

extern "C" void kernel_launch(void* const* d_in, const int* in_sizes, int n_in,
                              void* d_out, int out_size, void* d_ws, size_t ws_size,
                              hipStream_t stream) {
    const float* fm    = (const float*)d_in[0];
    const float* boxes = (const float*)d_in[1];
    const float* W1    = (const float*)d_in[2];
    const float* b1    = (const float*)d_in[3];
    const float* W2    = (const float*)d_in[4];
    const float* b2    = (const float*)d_in[5];
    const float* Wc    = (const float*)d_in[6];
    const float* bc    = (const float*)d_in[7];
    const float* Wb    = (const float*)d_in[8];
    const float* bb    = (const float*)d_in[9];
    float* out = (float*)d_out;
    char* ws = (char*)d_ws;

    const size_t XIB = (size_t)NROIS * (2*DD) * sizeof(unsigned short);  // 25,690,112
    const size_t P1B = (size_t)NP1 * MM * NN * sizeof(float);            // 33,554,432
    unsigned short* XI  = (unsigned short*)ws;
    float*          P1  = (float*)(ws + XIB);
    unsigned short* h1I = (unsigned short*)(ws + XIB + P1B);             // 262,144 B
    float*          P2  = (float*)(ws + XIB + P1B + 262144);             // 4,194,304 B

    hipFuncSetAttribute((const void*)fc1_gld,
                        hipFuncAttributeMaxDynamicSharedMemorySize, FC1_LDS);

    crop_kernel<<<dim3(NROIS, SS*SS), 512, 0, stream>>>(fm, boxes, XI);
    fc1_gld<<<dim3(NP1, 4), 256, FC1_LDS, stream>>>(XI, W1, P1);
    reduce_bias_split<<<(MM*NN)/256, 256, 0, stream>>>(P1, b1, h1I);
    fc_mfma<<<dim3(KC2, 8), 256, 0, stream>>>(h1I, W2, P2, 2*NN, KCH2);
    heads_kernel<<<NROIS, 256, 0, stream>>>(P2, b2, Wc, bc, Wb, bb, out);
}

// Round 17
// 124.483 us; speedup vs baseline: 1.3096x; 1.0604x over previous
//
#include <hip/hip_runtime.h>
#include <math.h>

#define SS 7
#define NROIS 64
#define CC 2048
#define DD (SS*SS*CC)   // 100352
#define MM 64
#define NN 1024
#define NP1 128         // fc1 partials (one per kc)
#define KC2 16          // fc2 k-chunks (KCH=64, nkt=2)
#define KCH2 64
#define W1COLS 256      // fc1 per-block n-tile
#define WSTRIDE 260     // LDS row stride in dwords (256 + 4 pad, 16B-aligned)
#define FC1_LDS (2 * 32 * WSTRIDE * 4)   // 66,560 B -> 2 blocks/CU
#define CPOL_NT 2       // gfx940+ CPol non-temporal bit (hint only)

typedef float f32x4 __attribute__((ext_vector_type(4)));
typedef __bf16 bf16x8 __attribute__((ext_vector_type(8)));
typedef unsigned int uintx4 __attribute__((ext_vector_type(4)));

// Barrier WITHOUT the vmcnt(0) drain (verified win in R7/R11/R12).
#define LDS_BARRIER() do {                                         \
    asm volatile("s_waitcnt lgkmcnt(0)" ::: "memory");             \
    __builtin_amdgcn_s_barrier();                                  \
} while (0)

__device__ __forceinline__ unsigned short f2bf(float f){
    unsigned u = __builtin_bit_cast(unsigned, f);
    u += 0x7fffu + ((u >> 16) & 1u);           // RNE
    return (unsigned short)(u >> 16);
}
__device__ __forceinline__ float bf2f(unsigned short h){
    unsigned u = ((unsigned)h) << 16;
    return __builtin_bit_cast(float, u);
}
__device__ __forceinline__ void splitpk(float v0, float v1, unsigned& h, unsigned& l){
    __bf16 h0 = (__bf16)v0, h1 = (__bf16)v1;
    float r0 = v0 - (float)h0, r1 = v1 - (float)h1;
    __bf16 l0 = (__bf16)r0, l1 = (__bf16)r1;
    h = (unsigned)__builtin_bit_cast(unsigned short, h0) |
        ((unsigned)__builtin_bit_cast(unsigned short, h1) << 16);
    l = (unsigned)__builtin_bit_cast(unsigned short, l0) |
        ((unsigned)__builtin_bit_cast(unsigned short, l1) << 16);
}

// A-plane layout: interleaved hi/lo, [row][k/8][hi:8 shorts | lo:8 shorts].

// ---------------- Stage 1: crop + bilinear resize -> interleaved bf16 -------
__global__ void crop_kernel(const float* __restrict__ fm,
                            const float* __restrict__ boxes,
                            unsigned short* __restrict__ XI) {
    int roi = blockIdx.x;
    int p   = blockIdx.y;         // 0..48
    int sy = p / SS, sx = p % SS;
    const float* b = boxes + roi * 4;
    float x1 = fmaxf(0.f, rintf(b[0]));
    float y1 = fmaxf(0.f, rintf(b[1]));
    float x2 = fminf(15.f, rintf(b[2]));
    float y2 = fminf(15.f, rintf(b[3]));
    float h = y2 - y1, w = x2 - x1;
    float iy = ((sy + 0.5f) * h) / 7.0f - 0.5f;
    float ix = ((sx + 0.5f) * w) / 7.0f - 0.5f;
    iy = fminf(fmaxf(iy, 0.f), h - 1.f);
    ix = fminf(fmaxf(ix, 0.f), w - 1.f);
    float y0 = floorf(iy), x0 = floorf(ix);
    float fy = iy - y0,   fx = ix - x0;
    int y0i = (int)(y1 + y0);
    int y1i = min(y0i + 1, (int)(y1 + h - 1.f));
    int x0i = (int)(x1 + x0);
    int x1i = min(x0i + 1, (int)(x1 + w - 1.f));

    int c = threadIdx.x * 4;      // k index within row: p*CC + c
    const float4 v00 = *(const float4*)(fm + ((size_t)(y0i*16 + x0i))*CC + c);
    const float4 v01 = *(const float4*)(fm + ((size_t)(y0i*16 + x1i))*CC + c);
    const float4 v10 = *(const float4*)(fm + ((size_t)(y1i*16 + x0i))*CC + c);
    const float4 v11 = *(const float4*)(fm + ((size_t)(y1i*16 + x1i))*CC + c);
    float gy = 1.f - fy, gx = 1.f - fx;
    float o[4];
    o[0] = (v00.x*gy + v10.x*fy)*gx + (v01.x*gy + v11.x*fy)*fx;
    o[1] = (v00.y*gy + v10.y*fy)*gx + (v01.y*gy + v11.y*fy)*fx;
    o[2] = (v00.z*gy + v10.z*fy)*gx + (v01.z*gy + v11.z*fy)*fx;
    o[3] = (v00.w*gy + v10.w*fy)*gx + (v01.w*gy + v11.w*fy)*fx;
    uint2 hv, lv;
    splitpk(o[0], o[1], hv.x, lv.x);
    splitpk(o[2], o[3], hv.y, lv.y);
    int k = p * CC + c;
    size_t off = (size_t)roi * (2*DD) + (size_t)(k >> 3) * 16 + (k & 7);
    *(uint2*)(XI + off)     = hv;
    *(uint2*)(XI + off + 8) = lv;
}

// ---------------- Stage 2a: fc1 double-buffered gld (R12 + NT on W) ---------
// Grid (128 kc, 4 nb) = 512 blocks = 2/CU (dynamic LDS 66.5 KB). 256 thr =
// 4 waves, wave tile 64m x 64n. Block kc owns 24-25 k-tiles (BK=32, 1 KB
// contiguous per W row). Double-buffered LDS + COUNTED vmcnt(8). W1 gld
// marked NON-TEMPORAL (CPol NT): 411 MB zero-reuse stream must not thrash
// the L3 that X (25.7 MB, ~8x logical reuse) and P1 live in.
// fp32 in LDS; bf16 hi/lo split at read. 3-term: D += Ah*Bh + Ah*Bl + Al*Bh.
__global__ __launch_bounds__(256, 2)
void fc1_gld(const unsigned short* __restrict__ AI,
             const float* __restrict__ Wm, float* __restrict__ P) {
    const int kc = blockIdx.x;                       // 0..127
    const int nb = blockIdx.y;                       // 0..3
    const int kt_cnt = 24 + (kc < 64 ? 1 : 0);
    const int k0 = (kc * 24 + (kc < 64 ? kc : 64)) * 32;

    const int t = threadIdx.x;                       // 0..255
    const int lane = t & 63, wv = t >> 6;
    const int ln = lane & 15;
    const int koff = (lane >> 4) * 8;

    extern __shared__ float WS[];                    // 2 x [32][WSTRIDE]

    f32x4 acc[16];                                   // [nf*4+mf], static idx
    #pragma unroll
    for (int i = 0; i < 16; ++i) acc[i] = (f32x4){0.f, 0.f, 0.f, 0.f};

    size_t abase[4];
    #pragma unroll
    for (int mf = 0; mf < 4; ++mf)
        abase[mf] = (size_t)(mf * 16 + ln) * (2*DD) + (size_t)(k0 + koff) * 2;

    bf16x8 Ah[4], Al[4];

    // per-wave W staging: rows wv*8 .. wv*8+7, ONE gld per row (1 KB/instr)
    const float* wtile = Wm + (size_t)k0 * NN + nb * W1COLS;
    auto issueW = [&](int kt, int buf) {
        const float* g0 = wtile + ((size_t)kt * 32 + wv * 8) * NN + (lane << 2);
        float* l0 = WS + buf * (32 * WSTRIDE) + (wv * 8) * WSTRIDE;
        #pragma unroll
        for (int rr = 0; rr < 8; ++rr) {
            __builtin_amdgcn_global_load_lds(
                (const __attribute__((address_space(1))) void*)(g0 + (size_t)rr * NN),
                (__attribute__((address_space(3))) void*)(l0 + rr * WSTRIDE),
                16, 0, CPOL_NT);
        }
    };

    issueW(0, 0);                                    // prologue: tile 0 -> buf 0

    for (int kt = 0; kt < kt_cnt; ++kt) {
        const int cur = kt & 1;
        // A fragments for tile kt FIRST (older than next-tile gld in vmcnt)
        #pragma unroll
        for (int mf = 0; mf < 4; ++mf) {
            Ah[mf] = *(const bf16x8*)(AI + abase[mf] + (size_t)kt * 64);
            Al[mf] = *(const bf16x8*)(AI + abase[mf] + (size_t)kt * 64 + 8);
        }
        // next tile into the other buffer (read-finished last iter, barrier'd)
        if (kt + 1 < kt_cnt) issueW(kt + 1, 1 - cur);
        // wait: everything except the 8 newest (= next-tile gld) has landed
        asm volatile("s_waitcnt vmcnt(8)" ::: "memory");
        __builtin_amdgcn_s_barrier();                // all waves' tile-kt rows in
        // ---- compute tile kt from buf[cur]
        const float* B = WS + cur * (32 * WSTRIDE);
        #pragma unroll
        for (int nf = 0; nf < 4; ++nf) {
            const int cb = koff * WSTRIDE + wv * 64 + nf * 16 + ln;
            float f0 = B[cb + 0*WSTRIDE];
            float f1 = B[cb + 1*WSTRIDE];
            float f2 = B[cb + 2*WSTRIDE];
            float f3 = B[cb + 3*WSTRIDE];
            float f4 = B[cb + 4*WSTRIDE];
            float f5 = B[cb + 5*WSTRIDE];
            float f6 = B[cb + 6*WSTRIDE];
            float f7 = B[cb + 7*WSTRIDE];
            unsigned h01,l01,h23,l23,h45,l45,h67,l67;
            splitpk(f0, f1, h01, l01);
            splitpk(f2, f3, h23, l23);
            splitpk(f4, f5, h45, l45);
            splitpk(f6, f7, h67, l67);
            bf16x8 Bh = __builtin_bit_cast(bf16x8, (uintx4){h01, h23, h45, h67});
            bf16x8 Bl = __builtin_bit_cast(bf16x8, (uintx4){l01, l23, l45, l67});
            #pragma unroll
            for (int mf = 0; mf < 4; ++mf) {
                acc[nf*4+mf] = __builtin_amdgcn_mfma_f32_16x16x32_bf16(Ah[mf], Bh, acc[nf*4+mf], 0, 0, 0);
                acc[nf*4+mf] = __builtin_amdgcn_mfma_f32_16x16x32_bf16(Ah[mf], Bl, acc[nf*4+mf], 0, 0, 0);
                acc[nf*4+mf] = __builtin_amdgcn_mfma_f32_16x16x32_bf16(Al[mf], Bh, acc[nf*4+mf], 0, 0, 0);
            }
        }
        LDS_BARRIER();    // all reads of buf[cur] done -> next iter may gld into it
    }

    // ---- write partials: D row = (lane>>4)*4 + i, col = lane&15 (verified)
    const int orb = (lane >> 4) * 4;
    #pragma unroll
    for (int nf = 0; nf < 4; ++nf) {
        int col = nb * W1COLS + wv * 64 + nf * 16 + ln;
        #pragma unroll
        for (int mf = 0; mf < 4; ++mf) {
            #pragma unroll
            for (int i = 0; i < 4; ++i) {
                int m = mf * 16 + orb + i;
                P[((size_t)kc * MM + m) * NN + col] = acc[nf*4+mf][i];
            }
        }
    }
}

// ---------------- Stage 2b: generic FC (fc2) via bf16x2-split MFMA ----------
__global__ __launch_bounds__(256, 2)
void fc_mfma(const unsigned short* __restrict__ AI,
             const float* __restrict__ Wm, float* __restrict__ P,
             int rstride /*shorts*/, int kchunk) {
    const int kc = blockIdx.x, nb = blockIdx.y;
    const int n0 = nb * 128;
    const int k0 = kc * kchunk;
    const int t = threadIdx.x;
    const int lane = t & 63, wv = t >> 6;
    const int ln = lane & 15;
    const int koff = (lane >> 4) * 8;
    const int kp = t & 15, no = t >> 4;

    __shared__ unsigned short WTh[128][34];
    __shared__ unsigned short WTl[128][34];

    f32x4 acc[8];
    #pragma unroll
    for (int i = 0; i < 8; ++i) acc[i] = (f32x4){0.f, 0.f, 0.f, 0.f};

    size_t abase[4];
    #pragma unroll
    for (int mf = 0; mf < 4; ++mf)
        abase[mf] = (size_t)(mf * 16 + ln) * rstride + (size_t)((k0 + koff) >> 3) * 16;

    const float* wbase = Wm + (size_t)k0 * NN + n0 + no * 8;

    float4 wa[4], wb[4];
    bf16x8 Aah[4], Aal[4], Abh[4], Abl[4];

    auto loadW = [&](int kt, float4* r) {
        const float* p = wbase + (size_t)(kt * 32 + 2 * kp) * NN;
        r[0] = *(const float4*)(p);
        r[1] = *(const float4*)(p + 4);
        r[2] = *(const float4*)(p + NN);
        r[3] = *(const float4*)(p + NN + 4);
    };
    auto loadA = [&](int kt, bf16x8* Ah, bf16x8* Al) {
        const size_t kb = (size_t)kt * 64;
        #pragma unroll
        for (int mf = 0; mf < 4; ++mf) {
            Ah[mf] = *(const bf16x8*)(AI + abase[mf] + kb);
            Al[mf] = *(const bf16x8*)(AI + abase[mf] + kb + 8);
        }
    };
    auto stageW = [&](const float4* r) {
        const float* r0 = (const float*)&r[0];
        const float* r1 = (const float*)&r[2];
        #pragma unroll
        for (int e = 0; e < 8; ++e) {
            int n = no * 8 + e;
            unsigned h, l;
            splitpk(r0[e], r1[e], h, l);
            *(unsigned*)&WTh[n][2 * kp] = h;
            *(unsigned*)&WTl[n][2 * kp] = l;
        }
    };

#define MFMA_PHASE(AH, AL)                                                     \
    {                                                                          \
        _Pragma("unroll")                                                      \
        for (int nf = 0; nf < 2; ++nf) {                                       \
            bf16x8 Bh = *(const bf16x8*)&WTh[wv * 32 + nf * 16 + ln][koff];    \
            bf16x8 Bl = *(const bf16x8*)&WTl[wv * 32 + nf * 16 + ln][koff];    \
            _Pragma("unroll")                                                  \
            for (int mf = 0; mf < 4; ++mf) {                                   \
                acc[nf*4+mf] = __builtin_amdgcn_mfma_f32_16x16x32_bf16(AH[mf], Bh, acc[nf*4+mf], 0, 0, 0); \
                acc[nf*4+mf] = __builtin_amdgcn_mfma_f32_16x16x32_bf16(AH[mf], Bl, acc[nf*4+mf], 0, 0, 0); \
                acc[nf*4+mf] = __builtin_amdgcn_mfma_f32_16x16x32_bf16(AL[mf], Bh, acc[nf*4+mf], 0, 0, 0); \
            }                                                                  \
        }                                                                      \
    }

    const int nkt = kchunk >> 5;
    loadW(0, wa);
    loadW(1, wb);
    loadA(0, Aah, Aal);
    loadA(1, Abh, Abl);

    for (int ktp = 0; ktp + 1 < nkt; ktp += 2) {
        LDS_BARRIER();
        stageW(wa);
        if (ktp + 2 < nkt) loadW(ktp + 2, wa);
        LDS_BARRIER();
        MFMA_PHASE(Aah, Aal);
        if (ktp + 2 < nkt) loadA(ktp + 2, Aah, Aal);
        LDS_BARRIER();
        stageW(wb);
        if (ktp + 3 < nkt) loadW(ktp + 3, wb);
        LDS_BARRIER();
        MFMA_PHASE(Abh, Abl);
        if (ktp + 3 < nkt) loadA(ktp + 3, Abh, Abl);
    }
    if (nkt & 1) {
        LDS_BARRIER();
        stageW(wa);
        LDS_BARRIER();
        MFMA_PHASE(Aah, Aal);
    }
#undef MFMA_PHASE

    const int orb = (lane >> 4) * 4;
    #pragma unroll
    for (int nf = 0; nf < 2; ++nf) {
        int col = n0 + wv * 32 + nf * 16 + ln;
        #pragma unroll
        for (int mf = 0; mf < 4; ++mf) {
            #pragma unroll
            for (int i = 0; i < 4; ++i) {
                int m = mf * 16 + orb + i;
                P[((size_t)kc * MM + m) * NN + col] = acc[nf*4+mf][i];
            }
        }
    }
}

// ---------------- Stage 3: reduce 128 partials + bias + relu -> interleaved -
__global__ void reduce_bias_split(const float* __restrict__ P,
                                  const float* __restrict__ bias,
                                  unsigned short* __restrict__ YI) {
    int idx = blockIdx.x * 256 + threadIdx.x;   // 0..65535
    int n = idx & (NN - 1);
    int m = idx >> 10;
    float s0 = bias[n], s1 = 0.f, s2 = 0.f, s3 = 0.f;
    float s4 = 0.f, s5 = 0.f, s6 = 0.f, s7 = 0.f;
    for (int kc = 0; kc < NP1; kc += 8) {
        s0 += P[(size_t)(kc + 0) * (MM*NN) + idx];
        s1 += P[(size_t)(kc + 1) * (MM*NN) + idx];
        s2 += P[(size_t)(kc + 2) * (MM*NN) + idx];
        s3 += P[(size_t)(kc + 3) * (MM*NN) + idx];
        s4 += P[(size_t)(kc + 4) * (MM*NN) + idx];
        s5 += P[(size_t)(kc + 5) * (MM*NN) + idx];
        s6 += P[(size_t)(kc + 6) * (MM*NN) + idx];
        s7 += P[(size_t)(kc + 7) * (MM*NN) + idx];
    }
    float s = ((s0 + s1) + (s2 + s3)) + ((s4 + s5) + (s6 + s7));
    s = fmaxf(s, 0.f);
    unsigned short h = f2bf(s);
    size_t off = (size_t)m * (2*NN) + (size_t)(n >> 3) * 16 + (n & 7);
    YI[off]     = h;
    YI[off + 8] = f2bf(s - bf2f(h));
}

// ---------------- Stage 4: fused P2-reduce + bias + relu + heads ------------
__global__ void heads_kernel(const float* __restrict__ P2,
                             const float* __restrict__ b2,
                             const float* __restrict__ Wc, const float* __restrict__ bc,
                             const float* __restrict__ Wb, const float* __restrict__ bb,
                             float* __restrict__ out) {
    int m = blockIdx.x;
    int t = threadIdx.x;   // 256
    float a[6] = {0,0,0,0,0,0};
    #pragma unroll
    for (int j = 0; j < 4; ++j) {
        int n = j * 256 + t;
        float s = b2[n];
        #pragma unroll
        for (int kc = 0; kc < KC2; ++kc)
            s += P2[((size_t)kc * MM + m) * NN + n];
        s = fmaxf(s, 0.f);
        a[0] += s * Wc[n*2 + 0];
        a[1] += s * Wc[n*2 + 1];
        a[2] += s * Wb[n*4 + 0];
        a[3] += s * Wb[n*4 + 1];
        a[4] += s * Wb[n*4 + 2];
        a[5] += s * Wb[n*4 + 3];
    }
    __shared__ float red[6][256];
    #pragma unroll
    for (int j = 0; j < 6; ++j) red[j][t] = a[j];
    __syncthreads();
    for (int s = 128; s > 0; s >>= 1) {
        if (t < s) {
            #pragma unroll
            for (int j = 0; j < 6; ++j) red[j][t] += red[j][t + s];
        }
        __syncthreads();
    }
    if (t == 0) {
        float l0 = red[0][0] + bc[0], l1 = red[1][0] + bc[1];
        float mx = fmaxf(l0, l1);
        float e0 = expf(l0 - mx), e1 = expf(l1 - mx);
        float inv = 1.f / (e0 + e1);
        out[m*2 + 0] = e0 * inv;
        out[m*2 + 1] = e1 * inv;
        out[128 + m*4 + 0] = red[2][0] + bb[0];
        out[128 + m*4 + 1] = red[3][0] + bb[1];
        out[128 + m*4 + 2] = red[4][0] + bb[2];
        out[128 + m*4 + 3] = red[5][0] + bb[3];
    }
}

extern "C" void kernel_launch(void* const* d_in, const int* in_sizes, int n_in,
                              void* d_out, int out_size, void* d_ws, size_t ws_size,
                              hipStream_t stream) {
    const float* fm    = (const float*)d_in[0];
    const float* boxes = (const float*)d_in[1];
    const float* W1    = (const float*)d_in[2];
    const float* b1    = (const float*)d_in[3];
    const float* W2    = (const float*)d_in[4];
    const float* b2    = (const float*)d_in[5];
    const float* Wc    = (const float*)d_in[6];
    const float* bc    = (const float*)d_in[7];
    const float* Wb    = (const float*)d_in[8];
    const float* bb    = (const float*)d_in[9];
    float* out = (float*)d_out;
    char* ws = (char*)d_ws;

    const size_t XIB = (size_t)NROIS * (2*DD) * sizeof(unsigned short);  // 25,690,112
    const size_t P1B = (size_t)NP1 * MM * NN * sizeof(float);            // 33,554,432
    unsigned short* XI  = (unsigned short*)ws;
    float*          P1  = (float*)(ws + XIB);
    unsigned short* h1I = (unsigned short*)(ws + XIB + P1B);             // 262,144 B
    float*          P2  = (float*)(ws + XIB + P1B + 262144);             // 4,194,304 B

    hipFuncSetAttribute((const void*)fc1_gld,
                        hipFuncAttributeMaxDynamicSharedMemorySize, FC1_LDS);

    crop_kernel<<<dim3(NROIS, SS*SS), 512, 0, stream>>>(fm, boxes, XI);
    fc1_gld<<<dim3(NP1, 4), 256, FC1_LDS, stream>>>(XI, W1, P1);
    reduce_bias_split<<<(MM*NN)/256, 256, 0, stream>>>(P1, b1, h1I);
    fc_mfma<<<dim3(KC2, 8), 256, 0, stream>>>(h1I, W2, P2, 2*NN, KCH2);
    heads_kernel<<<NROIS, 256, 0, stream>>>(P2, b2, Wc, bc, Wb, bb, out);
}